// Round 8
// baseline (368.456 us; speedup 1.0000x reference)
//
#include <hip/hip_runtime.h>
#include <hip/hip_fp16.h>
#include <stdint.h>

// ---------------------------------------------------------------------------
// GNNWithMoE: 2x GGNN(edge-embed + gather + GRU) -> soft MoE -> mean pool
// ALL float tensors fp32; ints int32; out fp32. GEMMs via bf16 MFMA.
//
// Round-16 (src-partitioned gather passes; round-15 post-mortem: 8->32
// in-flight loads was NEUTRAL -> miss path is queue-saturated; FETCH 95MB =
// every random row read misses (x16 6.4MB > 4MB L2/XCD, thrashed by streams).
// Only lever: FEWER misses):
//  * gather phase C runs 4 PASSES over source-node quarters (Q=ceil(N/4),
//    1.6MB of x16 per pass, fits L2/XCD with room for streaming traffic).
//    All blocks sweep quarters in order -> chip-wide read window shrinks to
//    ~1.6MB at a time -> 16x row reuse becomes L2 hits after first touch.
//    Pass masks rebuilt via ballot (no VGPR cost); 4-node interleave kept.
// Round-15: phased A/B/C/D gather pipeline. Round-14: fused 11 kernels -> 6.
// Round-12: fp16 row mirrors x16/h16. Round-11: XCC-id sub-bucket, workgroup-
// scope counter atomic (parked at L2 atomic-RMW floor). Round-10: int4 slot.
// Sub-bucket cap 8, ~Poisson(2); overflow edges handled in-fused (any input).
// Workspace (16B-aligned):
//   v[N*64] f32 | h[N*64] f32 | bkt[N*64] int4 | cur[8*N] i32 | ovfcnt[4] |
//   ovf[32768] | wbf[65792] bf16 | partial[B*PS*64] f32 | x16[N*64] fp16 |
//   h16[N*64] fp16
// ---------------------------------------------------------------------------

#define SUBCAP 8
#define OVF_MAX 32768
#define PS 16   // pool splits per graph

typedef __bf16 bf16x8 __attribute__((ext_vector_type(8)));
typedef float floatx4 __attribute__((ext_vector_type(4)));
typedef unsigned short us8 __attribute__((ext_vector_type(8)));

__device__ __forceinline__ unsigned short f2bf(float f){
  union { float f; unsigned u; } c; c.f = f;
  unsigned r = c.u + 0x7FFFu + ((c.u >> 16) & 1u);
  return (unsigned short)(r >> 16);
}
__device__ __forceinline__ float bf2f(unsigned short u){
  union { unsigned u; float f; } c; c.u = ((unsigned)u) << 16; return c.f;
}
__device__ __forceinline__ unsigned short f2h(float f){
  return __half_as_ushort(__float2half(f));
}
__device__ __forceinline__ float h2f(unsigned short u){
  return __half2float(__ushort_as_half(u));
}
__device__ __forceinline__ float sigm(float x){ return 1.f/(1.f + __expf(-x)); }

// fused: weight fp32->bf16 conversion + zero cur/ovfcnt + x -> fp16 mirror
__global__ void k_init(const float* __restrict__ s0, const float* __restrict__ s1,
                       const float* __restrict__ s2, const float* __restrict__ s3,
                       const float* __restrict__ s4, const float* __restrict__ s5,
                       unsigned short* __restrict__ dst,
                       int* __restrict__ cur, int* __restrict__ ovfcnt, int N8,
                       const float* __restrict__ xin, unsigned short* __restrict__ x16,
                       int nTot){
  int i = blockIdx.x*blockDim.x + threadIdx.x;
  if (i < N8) cur[i] = 0;
  if (i == 0){ ovfcnt[0] = 0; }
  int base = i*8;
  if (base < nTot){
    const float4* xp = (const float4*)(xin + base);
    float4 a = xp[0], b = xp[1];
    us8 t;
    t[0]=f2h(a.x); t[1]=f2h(a.y); t[2]=f2h(a.z); t[3]=f2h(a.w);
    t[4]=f2h(b.x); t[5]=f2h(b.y); t[6]=f2h(b.z); t[7]=f2h(b.w);
    *(us8*)(x16 + base) = t;
  }
  if (i >= 65792) return;
  const float* s; int off;
  if      (i < 12288){ s = s0; off = i; }
  else if (i < 24576){ s = s1; off = i - 12288; }
  else if (i < 36864){ s = s2; off = i - 24576; }
  else if (i < 49152){ s = s3; off = i - 36864; }
  else if (i < 49408){ s = s4; off = i - 49152; }
  else               { s = s5; off = i - 49408; }
  dst[i] = f2bf(s[off]);
}

// sub-bucket = PHYSICAL XCD id; workgroup-scope counter atomic (local TCC).
// At the L2 atomic-RMW rate floor (~0.8/cy/XCD, r10-r13) -- parked.
__global__ void k_bucket(const int* __restrict__ ei, const float* __restrict__ ea,
                         int* __restrict__ cur, int4* __restrict__ bkt,
                         int* __restrict__ ovfcnt, int* __restrict__ ovf,
                         int E, int N){
  unsigned xcc;
  asm volatile("s_getreg_b32 %0, hwreg(HW_REG_XCC_ID)" : "=s"(xcc));
  int sub = (int)(xcc & 7u);         // physical XCD id (m09: 0..7)
  int base = blockIdx.x*512;
#pragma unroll
  for (int half = 0; half < 2; ++half){
    int e = base + half*256 + threadIdx.x;
    if (e >= E) continue;
    int s = ei[e];
    int d = ei[E + e];
    size_t sb = (size_t)sub*N + d;
    int pos = __hip_atomic_fetch_add(&cur[sb], 1, __ATOMIC_RELAXED,
                                     __HIP_MEMORY_SCOPE_WORKGROUP);
    if (pos < SUBCAP){
      float4 v = *(const float4*)(ea + (size_t)e*4);
      int4 p;
      p.x = s;
      p.y = (int)(((unsigned)f2bf(v.y) << 16) | (unsigned)f2bf(v.x));
      p.z = (int)(((unsigned)f2bf(v.w) << 16) | (unsigned)f2bf(v.z));
      p.w = 0;
      bkt[sb*SUBCAP + pos] = p;
    } else {
      int o = atomicAdd(ovfcnt, 1);   // cross-XCD counter: stays device scope
      if (o < OVF_MAX) ovf[o] = e;
    }
  }
}

// 8-deep row-load batch for one node's mask; all lanes load element d of the
// extracted rows. Loads are independent -> up to 8 in flight per node.
#define GATHER8(MM, SRC, A)                                                \
  {                                                                        \
    unsigned long long m2 = (MM);                                          \
    if (m2){                                                               \
      int l0=(int)__builtin_ctzll(m2); m2 &= m2-1;                         \
      A[0] = h2f(x16[(size_t)__shfl((SRC), l0)*64 + d]);                   \
      if (m2){                                                             \
        int l1=(int)__builtin_ctzll(m2); m2 &= m2-1;                       \
        A[1] = h2f(x16[(size_t)__shfl((SRC), l1)*64 + d]);                 \
        if (m2){                                                           \
          int l2=(int)__builtin_ctzll(m2); m2 &= m2-1;                     \
          A[2] = h2f(x16[(size_t)__shfl((SRC), l2)*64 + d]);               \
          if (m2){                                                         \
            int l3=(int)__builtin_ctzll(m2); m2 &= m2-1;                   \
            A[3] = h2f(x16[(size_t)__shfl((SRC), l3)*64 + d]);             \
            if (m2){                                                       \
              int l4=(int)__builtin_ctzll(m2); m2 &= m2-1;                 \
              A[4] = h2f(x16[(size_t)__shfl((SRC), l4)*64 + d]);           \
              if (m2){                                                     \
                int l5=(int)__builtin_ctzll(m2); m2 &= m2-1;               \
                A[5] = h2f(x16[(size_t)__shfl((SRC), l5)*64 + d]);         \
                if (m2){                                                   \
                  int l6=(int)__builtin_ctzll(m2); m2 &= m2-1;             \
                  A[6] = h2f(x16[(size_t)__shfl((SRC), l6)*64 + d]);       \
                  if (m2){                                                 \
                    int l7=(int)__builtin_ctzll(m2); m2 &= m2-1;           \
                    A[7] = h2f(x16[(size_t)__shfl((SRC), l7)*64 + d]);     \
                  }                                                        \
                }                                                          \
              }                                                            \
            }                                                              \
          }                                                                \
        }                                                                  \
      }                                                                    \
    }                                                                      \
    (MM) = m2;                                                             \
  }

// gather 4 nodes per wave into LDS mt rows w*4..w*4+3; row-gather runs in 4
// src-quarter passes (chip-wide L2 working-set shrink), nodes interleaved
// within a pass; then apply this wave's overflow edges. Lane = dim d.
__device__ __forceinline__ void gather4_ovf(
    const int* __restrict__ cur, const int4* __restrict__ bkt,
    const float* __restrict__ xin, const unsigned short* __restrict__ x16,
    const float* __restrict__ w_edge, const float* __restrict__ b_edge,
    const int* __restrict__ ei, const float* __restrict__ ea,
    const int* __restrict__ ovf, int cnt, int E,
    float (*mt)[68], int tile, int w, int lane, int N){
  int d = lane;
  int sub = d >> 3, k = d & 7;
  float4 wv = *(const float4*)(w_edge + d*4);
  float be = b_edge[d];
  int n0 = tile*16 + w*4;
  int Q = (N + 3) >> 2;   // src-quarter size (~1.6MB of x16 per pass)

  // ---- phase A: 4x cur + 4x self-row loads (8 independent, in flight)
  int nc[4]; int myc[4]; float selfv[4];
#pragma unroll
  for (int nl = 0; nl < 4; ++nl){
    int n = n0 + nl;
    nc[nl] = n < N ? n : N-1;
    myc[nl] = cur[(size_t)sub*N + nc[nl]];
    selfv[nl] = xin[(size_t)nc[nl]*64 + d];
  }
  // ---- phase B: valid + 4x bucket-slot loads (in flight) + quarter ids
  bool valid[4]; int4 ps[4];
#pragma unroll
  for (int nl = 0; nl < 4; ++nl){
    valid[nl] = k < min(myc[nl], SUBCAP);
    int4 z; z.x = 0; z.y = 0; z.z = 0; z.w = 0;
    ps[nl] = valid[nl] ? bkt[((size_t)sub*N + nc[nl])*SUBCAP + k] : z;
  }
  int src[4]; int qid[4];
#pragma unroll
  for (int nl = 0; nl < 4; ++nl){
    src[nl] = ps[nl].x;
    qid[nl] = (src[nl] >= Q) + (src[nl] >= 2*Q) + (src[nl] >= 3*Q);
  }
  // ---- phase C: 4 src-quarter passes; nodes interleaved within each pass
  float acc[4];
#pragma unroll
  for (int nl = 0; nl < 4; ++nl) acc[nl] = 0.f;
#pragma unroll
  for (int q = 0; q < 4; ++q){
    unsigned long long mm[4];
#pragma unroll
    for (int nl = 0; nl < 4; ++nl)
      mm[nl] = __ballot(valid[nl] && (qid[nl] == q));
    while (mm[0] | mm[1] | mm[2] | mm[3]){
      float a[4][8];
#pragma unroll
      for (int nl = 0; nl < 4; ++nl){
#pragma unroll
        for (int jj = 0; jj < 8; ++jj) a[nl][jj] = 0.f;
        GATHER8(mm[nl], src[nl], a[nl]);
      }
#pragma unroll
      for (int nl = 0; nl < 4; ++nl)
        acc[nl] += ((a[nl][0]+a[nl][1])+(a[nl][2]+a[nl][3]))
                 + ((a[nl][4]+a[nl][5])+(a[nl][6]+a[nl][7]));
    }
  }
  // ---- phase D: deg + ea butterflies (VALU, off the load critical path)
#pragma unroll
  for (int nl = 0; nl < 4; ++nl){
    int contrib = (k == 0) ? myc[nl] : 0;
#pragma unroll
    for (int off = 1; off < 64; off <<= 1) contrib += __shfl_xor(contrib, off);
    float ex = 0.f, ey = 0.f, ez = 0.f, ew = 0.f;
    if (valid[nl]){
      ex = bf2f((unsigned short)(ps[nl].y & 0xffff));
      ey = bf2f((unsigned short)(((unsigned)ps[nl].y) >> 16));
      ez = bf2f((unsigned short)(ps[nl].z & 0xffff));
      ew = bf2f((unsigned short)(((unsigned)ps[nl].z) >> 16));
    }
#pragma unroll
    for (int off = 1; off < 64; off <<= 1){
      ex += __shfl_xor(ex, off);
      ey += __shfl_xor(ey, off);
      ez += __shfl_xor(ez, off);
      ew += __shfl_xor(ew, off);
    }
    mt[w*4 + nl][d] = selfv[nl] + (float)(contrib + 1) * be + acc[nl]
                    + ex*wv.x + ey*wv.y + ez*wv.z + ew*wv.w;
  }
  // ---- overflow edges for rows owned by this wave (identical to old k_ovf)
  int lo = tile*16;
  for (int base = 0; base < cnt; base += 64){
    int idx = base + lane;
    int eid = (idx < cnt) ? ovf[idx] : -1;
    int dst = (eid >= 0) ? ei[(size_t)E + eid] : -1;
    int rel = dst - lo;
    bool hit = (eid >= 0) && (rel >= 0) && (rel < 16) && ((rel >> 2) == w);
    unsigned long long hm = __ballot(hit);
    while (hm){
      int l = (int)__builtin_ctzll(hm); hm &= hm - 1;
      int e2 = __shfl(eid, l);
      int r2 = __shfl(rel, l);
      int s2 = ei[e2];
      float4 v = *(const float4*)(ea + (size_t)e2*4);
      float addv = xin[(size_t)s2*64 + d] + v.x*wv.x + v.y*wv.y + v.z*wv.z + v.w*wv.w;
      mt[r2][d] += addv;
    }
  }
}

// GRU MFMA core: wave j owns output cols [16j,16j+16) = w-row-blocks {j,j+4,j+8}.
// A-frags from LDS mt ([16][68] pad: 2-way banks, 272B rows 16B-aligned).
__device__ __forceinline__ void gru3(
    const float (*mt)[68], const float* __restrict__ x,
    const unsigned short* __restrict__ wih, const unsigned short* __restrict__ whh,
    int tile, int j, int col, int quad, int N,
    floatx4* ai, floatx4* ah){
  int na = tile*16 + col; if (na > N-1) na = N-1;
  bf16x8 am[2], ax[2];
#pragma unroll
  for (int ks = 0; ks < 2; ++ks){
    int kb = ks*32 + quad*8;
    const float* mrow = &mt[col][kb];
    float4 lo = *(const float4*)mrow, hi = *(const float4*)(mrow + 4);
    us8 tm;
    tm[0]=f2bf(lo.x); tm[1]=f2bf(lo.y); tm[2]=f2bf(lo.z); tm[3]=f2bf(lo.w);
    tm[4]=f2bf(hi.x); tm[5]=f2bf(hi.y); tm[6]=f2bf(hi.z); tm[7]=f2bf(hi.w);
    am[ks] = __builtin_bit_cast(bf16x8, tm);
    const float4* xp = (const float4*)(x + (size_t)na*64 + kb);
    float4 xlo = xp[0], xhi = xp[1];
    us8 tx;
    tx[0]=f2bf(xlo.x); tx[1]=f2bf(xlo.y); tx[2]=f2bf(xlo.z); tx[3]=f2bf(xlo.w);
    tx[4]=f2bf(xhi.x); tx[5]=f2bf(xhi.y); tx[6]=f2bf(xhi.z); tx[7]=f2bf(xhi.w);
    ax[ks] = __builtin_bit_cast(bf16x8, tx);
  }
#pragma unroll
  for (int g = 0; g < 3; ++g){ ai[g] = (floatx4)0.f; ah[g] = (floatx4)0.f; }
#pragma unroll
  for (int g = 0; g < 3; ++g){
    int r = (g*4 + j)*16 + col;
#pragma unroll
    for (int ks = 0; ks < 2; ++ks){
      int kb = ks*32 + quad*8;
      bf16x8 bi = __builtin_bit_cast(bf16x8, *(const us8*)(wih + (size_t)r*64 + kb));
      ai[g] = __builtin_amdgcn_mfma_f32_16x16x32_bf16(am[ks], bi, ai[g], 0,0,0);
      bf16x8 bh = __builtin_bit_cast(bf16x8, *(const us8*)(whh + (size_t)r*64 + kb));
      ah[g] = __builtin_amdgcn_mfma_f32_16x16x32_bf16(ax[ks], bh, ah[g], 0,0,0);
    }
  }
}

// Layer 1: gather + ovf + GRU -> h (fp32) + h16 (fp16 mirror). Reads x only.
__global__ void __launch_bounds__(256) k_fused1(
    const int* __restrict__ cur, const int4* __restrict__ bkt,
    const float* __restrict__ x, const unsigned short* __restrict__ x16,
    const float* __restrict__ w_edge, const float* __restrict__ b_edge,
    const int* __restrict__ ei, const float* __restrict__ ea,
    const int* __restrict__ ovf, const int* __restrict__ ovfcnt, int E,
    const unsigned short* __restrict__ wih, const unsigned short* __restrict__ whh,
    const float* __restrict__ b_ih, const float* __restrict__ b_hh,
    float* __restrict__ hout, unsigned short* __restrict__ h16out,
    int tiles, int N){
  __shared__ __align__(16) float mt[16][68];
  int tile = blockIdx.x; if (tile >= tiles) return;
  int w = threadIdx.x >> 6, lane = threadIdx.x & 63;
  int cnt = *ovfcnt; if (cnt > OVF_MAX) cnt = OVF_MAX;
  gather4_ovf(cur, bkt, x, x16, w_edge, b_edge, ei, ea, ovf, cnt, E,
              mt, tile, w, lane, N);
  __syncthreads();   // mt complete across waves

  int col = lane & 15, quad = lane >> 4, j = w;
  floatx4 ai[3], ah[3];
  gru3(mt, x, wih, whh, tile, j, col, quad, N, ai, ah);

  int dd = j*16 + col;
  float bir = b_ih[dd],      bhr = b_hh[dd];
  float biz = b_ih[64+dd],   bhz = b_hh[64+dd];
  float bin = b_ih[128+dd],  bhn = b_hh[128+dd];
#pragma unroll
  for (int rg = 0; rg < 4; ++rg){
    int node = tile*16 + quad*4 + rg;
    if (node >= N) continue;
    float rr = sigm(ai[0][rg] + bir + ah[0][rg] + bhr);
    float zz = sigm(ai[1][rg] + biz + ah[1][rg] + bhz);
    float nn = tanhf(ai[2][rg] + bin + rr*(ah[2][rg] + bhn));
    float xv = x[(size_t)node*64 + dd];
    float hv = fmaxf((1.f - zz)*nn + zz*xv, 0.f);
    hout[(size_t)node*64 + dd] = hv;
    h16out[(size_t)node*64 + dd] = f2h(hv);
  }
}

// Layer 2 + MoE: gather + ovf + GRU -> bf16 h-frags in swizzled LDS -> MoE -> v.
// Reads h/h16 only (no in-place hazard); writes v only.
__global__ void __launch_bounds__(256) k_fused2(
    const int* __restrict__ cur, const int4* __restrict__ bkt,
    const float* __restrict__ h, const unsigned short* __restrict__ h16,
    const float* __restrict__ w_edge, const float* __restrict__ b_edge,
    const int* __restrict__ ei, const float* __restrict__ ea,
    const int* __restrict__ ovf, const int* __restrict__ ovfcnt, int E,
    const unsigned short* __restrict__ wih, const unsigned short* __restrict__ whh,
    const float* __restrict__ b_ih, const float* __restrict__ b_hh,
    const unsigned short* __restrict__ gate_w, const float* __restrict__ gate_b,
    const unsigned short* __restrict__ exp_w,  const float* __restrict__ exp_b,
    float* __restrict__ v_out, int tiles, int N){
  __shared__ __align__(16) float mt[16][68];
  __shared__ __align__(16) unsigned short ht16s[1024];  // bf16, XOR-swizzled
  __shared__ float gsm[16][4];
  __shared__ float vsm[4][16][65];
  int tile = blockIdx.x; if (tile >= tiles) return;
  int w = threadIdx.x >> 6, lane = threadIdx.x & 63;
  int cnt = *ovfcnt; if (cnt > OVF_MAX) cnt = OVF_MAX;
  gather4_ovf(cur, bkt, h, h16, w_edge, b_edge, ei, ea, ovf, cnt, E,
              mt, tile, w, lane, N);
  __syncthreads();   // mt complete

  int col = lane & 15, quad = lane >> 4, j = w;
  floatx4 ai[3], ah[3];
  gru3(mt, h, wih, whh, tile, j, col, quad, N, ai, ah);

  int dd = j*16 + col;
  {
    float bir = b_ih[dd],      bhr = b_hh[dd];
    float biz = b_ih[64+dd],   bhz = b_hh[64+dd];
    float bin = b_ih[128+dd],  bhn = b_hh[128+dd];
#pragma unroll
    for (int rg = 0; rg < 4; ++rg){
      int nloc = quad*4 + rg;
      int node = tile*16 + nloc;
      int na2 = node < N ? node : N-1;
      float rr = sigm(ai[0][rg] + bir + ah[0][rg] + bhr);
      float zz = sigm(ai[1][rg] + biz + ah[1][rg] + bhz);
      float nn = tanhf(ai[2][rg] + bin + rr*(ah[2][rg] + bhn));
      float xv = h[(size_t)na2*64 + dd];
      float hv = fmaxf((1.f - zz)*nn + zz*xv, 0.f);
      // swizzled bf16 store for the MoE A-fragment ((node&7)<<4 XOR: 2-way max)
      int addr = (nloc*128 + dd*2) ^ ((nloc & 7) << 4);
      *(unsigned short*)((char*)ht16s + addr) = f2bf(hv);
    }
  }
  __syncthreads();   // h-tile ready

  // ---- MoE phase: wave j = expert j; wave 0 also does the gate ----
  bf16x8 a2[2];
#pragma unroll
  for (int ks = 0; ks < 2; ++ks){
    int badd = (col*128 + ks*64 + quad*16) ^ ((col & 7) << 4);
    a2[ks] = __builtin_bit_cast(bf16x8, *(const us8*)((const char*)ht16s + badd));
  }
  if (j == 0){
    floatx4 accg = (floatx4)0.f;
#pragma unroll
    for (int ks = 0; ks < 2; ++ks){
      int kb = ks*32 + quad*8;
      us8 braw = {0,0,0,0,0,0,0,0};
      if (col < 4) braw = *(const us8*)(gate_w + col*64 + kb);
      accg = __builtin_amdgcn_mfma_f32_16x16x32_bf16(a2[ks], __builtin_bit_cast(bf16x8, braw), accg, 0,0,0);
    }
    if (col < 4){
      float gb = gate_b[col];
#pragma unroll
      for (int rg = 0; rg < 4; ++rg) gsm[quad*4+rg][col] = accg[rg] + gb;
    }
  }
  floatx4 acc2[4];
#pragma unroll
  for (int nt = 0; nt < 4; ++nt) acc2[nt] = (floatx4)0.f;
#pragma unroll
  for (int nt = 0; nt < 4; ++nt)
#pragma unroll
    for (int ks = 0; ks < 2; ++ks){
      int kb = ks*32 + quad*8;
      bf16x8 b = __builtin_bit_cast(bf16x8,
          *(const us8*)(exp_w + ((size_t)j*64 + nt*16 + col)*64 + kb));
      acc2[nt] = __builtin_amdgcn_mfma_f32_16x16x32_bf16(a2[ks], b, acc2[nt], 0,0,0);
    }
  __syncthreads();   // gsm ready

#pragma unroll
  for (int rg = 0; rg < 4; ++rg){
    int nrow = quad*4 + rg;
    float g0=gsm[nrow][0], g1=gsm[nrow][1], g2=gsm[nrow][2], g3=gsm[nrow][3];
    float mx = fmaxf(fmaxf(g0,g1), fmaxf(g2,g3));
    float e0=__expf(g0-mx), e1=__expf(g1-mx), e2=__expf(g2-mx), e3=__expf(g3-mx);
    float we = ((j==0)?e0:(j==1)?e1:(j==2)?e2:e3) / (e0+e1+e2+e3);
#pragma unroll
    for (int nt = 0; nt < 4; ++nt){
      int o = nt*16 + col;
      vsm[j][nrow][o] = we * fmaxf(acc2[nt][rg] + exp_b[j*64 + o], 0.f);
    }
  }
  __syncthreads();   // vsm ready

  for (int idx = threadIdx.x; idx < 1024; idx += 256){
    int nrow = idx >> 6, o = idx & 63;
    int node = tile*16 + nrow;
    if (node < N)
      v_out[(size_t)node*64 + o] = vsm[0][nrow][o] + vsm[1][nrow][o]
                                 + vsm[2][nrow][o] + vsm[3][nrow][o];
  }
}

__device__ __forceinline__ int lower_bound_i(const int* __restrict__ a, int n, int key){
  int lo = 0, hi = n;
  while (lo < hi){ int mid = (lo + hi) >> 1; if (a[mid] < key) lo = mid + 1; else hi = mid; }
  return lo;
}

// stage 1: B*PS blocks; block (g,s) reduces 1/PS of graph g's nodes.
__global__ void __launch_bounds__(256) k_pool(
    const float* __restrict__ v, const int* __restrict__ batch, int N,
    float* __restrict__ partial){
  __shared__ float red[4][64];
  int g = blockIdx.x / PS, s = blockIdx.x % PS;
  int t = threadIdx.x, d = t & 63, r = t >> 6;
  int start = lower_bound_i(batch, N, g);
  int end   = lower_bound_i(batch, N, g + 1);
  int len = end - start;
  int per = (len + PS - 1) / PS;
  int s0 = start + s*per;
  int s1 = s0 + per; if (s1 > end) s1 = end;
  float acc = 0.f;
  for (int i = s0 + r; i < s1; i += 4)
    acc += v[(size_t)i*64 + d];
  red[r][d] = acc;
  __syncthreads();
  if (r == 0)
    partial[(size_t)blockIdx.x*64 + d] = red[0][d] + red[1][d] + red[2][d] + red[3][d];
}

// stage 2: B blocks; sum PS partials, mean, write emb twice + logits head.
__global__ void __launch_bounds__(64) k_head(
    const float* __restrict__ partial, const int* __restrict__ batch, int N, int B,
    const float* __restrict__ ldxb,
    const float* __restrict__ proj_w, const float* __restrict__ proj_b,
    const float* __restrict__ fc_w, const float* __restrict__ fc_b,
    float* __restrict__ out){
  __shared__ float ges[64];
  int b = blockIdx.x, d = threadIdx.x;
  int start = lower_bound_i(batch, N, b);
  int end   = lower_bound_i(batch, N, b + 1);
  float sum = 0.f;
#pragma unroll
  for (int s = 0; s < PS; ++s)
    sum += partial[((size_t)b*PS + s)*64 + d];
  float ge = sum / fmaxf((float)(end - start), 1.f);
  ges[d] = ge;
  out[(size_t)b*64 + d]                = ge;
  out[(size_t)B*64 + (size_t)b*64 + d] = ge;
  __syncthreads();
  if (d < 10){
    float acc = fc_b[d];
    float fl = ldxb[b];
    const float* fr = fc_w + d*164;
    for (int p = 0; p < 100; ++p) acc += (fl*proj_w[p] + proj_b[p]) * fr[p];
    for (int dd = 0; dd < 64; ++dd) acc += ges[dd]*fr[100 + dd];
    out[(size_t)B*128 + (size_t)b*10 + d] = acc;
  }
}

extern "C" void kernel_launch(void* const* d_in, const int* in_sizes, int n_in,
                              void* d_out, int out_size, void* d_ws, size_t ws_size,
                              hipStream_t stream){
  const float* x      = (const float*)d_in[0];
  const int*   ei     = (const int*)d_in[1];
  const float* ea     = (const float*)d_in[2];
  const int*   batch  = (const int*)d_in[3];
  const float* ldxb   = (const float*)d_in[4];
  const float* w_edge1= (const float*)d_in[5];
  const float* b_edge1= (const float*)d_in[6];
  const float* w_ih1  = (const float*)d_in[7];
  const float* w_hh1  = (const float*)d_in[8];
  const float* b_ih1  = (const float*)d_in[9];
  const float* b_hh1  = (const float*)d_in[10];
  const float* w_edge2= (const float*)d_in[11];
  const float* b_edge2= (const float*)d_in[12];
  const float* w_ih2  = (const float*)d_in[13];
  const float* w_hh2  = (const float*)d_in[14];
  const float* b_ih2  = (const float*)d_in[15];
  const float* b_hh2  = (const float*)d_in[16];
  const float* gate_w = (const float*)d_in[17];
  const float* gate_b = (const float*)d_in[18];
  const float* exp_w  = (const float*)d_in[19];
  const float* exp_b  = (const float*)d_in[20];
  const float* proj_w = (const float*)d_in[21];
  const float* proj_b = (const float*)d_in[22];
  const float* fc_w   = (const float*)d_in[23];
  const float* fc_b   = (const float*)d_in[24];
  float* out = (float*)d_out;

  int N = in_sizes[0] / 64;
  int E = in_sizes[1] / 2;
  int B = in_sizes[4];
  int tiles = (N + 15) / 16;
  int nTot = N * 64;

  // workspace layout (all segment sizes multiples of 16B)
  float*   v       = (float*)d_ws;                      // N*64 f32 (MoE output)
  float*   h       = v + (size_t)nTot;                  // N*64 f32
  int4*    bkt     = (int4*)(h + (size_t)nTot);         // N*64 int4 {src,ea01,ea23,0}
  int*     cur     = (int*)(bkt + (size_t)nTot);        // 8*N i32   [sub*N+n]
  int*     ovfcnt  = cur + (size_t)N*8;                 // 4 i32 (padded)
  int*     ovf     = ovfcnt + 4;                        // OVF_MAX i32
  unsigned short* wbf = (unsigned short*)(ovf + OVF_MAX); // 65792 bf16
  float*   partial = (float*)(wbf + 65792);             // B*PS*64 f32
  unsigned short* x16 = (unsigned short*)(partial + (size_t)B*PS*64); // N*64 fp16
  unsigned short* h16 = x16 + (size_t)nTot;             // N*64 fp16
  unsigned short* wih1bf = wbf;
  unsigned short* whh1bf = wbf + 12288;
  unsigned short* wih2bf = wbf + 24576;
  unsigned short* whh2bf = wbf + 36864;
  unsigned short* gatebf = wbf + 49152;
  unsigned short* expbf  = wbf + 49408;

  dim3 blk(256);
  int edgeBlocks = (E + 511)/512;       // 2 edges per thread
  int N8 = N*8;
  int initThreads = N8 > 65792 ? N8 : 65792;
  if (nTot/8 > initThreads) initThreads = nTot/8;
  int initBlocks = (initThreads + 255)/256;

  k_init<<<initBlocks, blk, 0, stream>>>(w_ih1, w_hh1, w_ih2, w_hh2, gate_w, exp_w,
                                         wbf, cur, ovfcnt, N8, x, x16, nTot);
  k_bucket<<<edgeBlocks, blk, 0, stream>>>(ei, ea, cur, bkt, ovfcnt, ovf, E, N);
  // ---- layer 1: gather + ovf + GRU fused ----
  k_fused1<<<tiles, blk, 0, stream>>>(cur, bkt, x, x16, w_edge1, b_edge1,
                                      ei, ea, ovf, ovfcnt, E,
                                      wih1bf, whh1bf, b_ih1, b_hh1,
                                      h, h16, tiles, N);
  // ---- layer 2 + MoE fused ----
  k_fused2<<<tiles, blk, 0, stream>>>(cur, bkt, h, h16, w_edge2, b_edge2,
                                      ei, ea, ovf, ovfcnt, E,
                                      wih2bf, whh2bf, b_ih2, b_hh2,
                                      gatebf, gate_b, expbf, exp_b,
                                      v, tiles, N);
  // ---- two-stage segmented-mean pool + heads ----
  k_pool<<<B*PS, blk, 0, stream>>>(v, batch, N, partial);
  k_head<<<B, 64, 0, stream>>>(partial, batch, N, B, ldxb, proj_w, proj_b, fc_w, fc_b, out);
}

// Round 9
// 339.162 us; speedup vs baseline: 1.0864x; 1.0864x over previous
//
#include <hip/hip_runtime.h>
#include <hip/hip_fp16.h>
#include <stdint.h>

// ---------------------------------------------------------------------------
// GNNWithMoE: 2x GGNN(edge-embed + gather + GRU) -> soft MoE -> mean pool
// ALL float tensors fp32; ints int32; out fp32. GEMMs via bf16 MFMA.
//
// Round-17 (bkt line-traffic cut; round-16 post-mortem: src-quarter passes
// NULL -- blocks desync, chip-wide window never shrinks; removed. Decomposed
// FETCH 93.5MB: ~44MB is bkt slot LINES (8 subs x 128B/node for ~13MB of
// valid slots) -- that's the over-fetch to cut, the 128B/edge row read is
// pure payload at ~65% cache absorption already):
//  * 4 sub-buckets x 16 slots (sub = xcc>>1, SLOTS=16): valid slots (lam=4)
//    sit in the first ~64B of one contiguous 256B group -> bkt read lines
//    ~44 -> ~15MB/layer; k_bucket scatter writes concentrate 2x too.
//    Overflow P(X>16|lam=4)~3e-7. Counter atomic -> device scope (spans 2
//    XCDs; scope was proven neutral in r11). Lane map: sub=d>>4, k=d&15.
// Round-15: phased A/B/C/D gather pipeline (kept, single-pass C).
// Round-14: fused 11 kernels -> 6. Round-12: fp16 row mirrors x16/h16.
// Round-10: int4 bucket slot {src, ea01, ea23, pad}.
// Workspace (16B-aligned):
//   v[N*64] f32 | h[N*64] f32 | bkt[N*64] int4 | cur[8*N] i32 (4N used) |
//   ovfcnt[4] | ovf[32768] | wbf[65792] bf16 | partial[B*PS*64] f32 |
//   x16[N*64] fp16 | h16[N*64] fp16
// ---------------------------------------------------------------------------

#define SLOTS 16
#define OVF_MAX 32768
#define PS 16   // pool splits per graph

typedef __bf16 bf16x8 __attribute__((ext_vector_type(8)));
typedef float floatx4 __attribute__((ext_vector_type(4)));
typedef unsigned short us8 __attribute__((ext_vector_type(8)));

__device__ __forceinline__ unsigned short f2bf(float f){
  union { float f; unsigned u; } c; c.f = f;
  unsigned r = c.u + 0x7FFFu + ((c.u >> 16) & 1u);
  return (unsigned short)(r >> 16);
}
__device__ __forceinline__ float bf2f(unsigned short u){
  union { unsigned u; float f; } c; c.u = ((unsigned)u) << 16; return c.f;
}
__device__ __forceinline__ unsigned short f2h(float f){
  return __half_as_ushort(__float2half(f));
}
__device__ __forceinline__ float h2f(unsigned short u){
  return __half2float(__ushort_as_half(u));
}
__device__ __forceinline__ float sigm(float x){ return 1.f/(1.f + __expf(-x)); }

// fused: weight fp32->bf16 conversion + zero cur/ovfcnt + x -> fp16 mirror
__global__ void k_init(const float* __restrict__ s0, const float* __restrict__ s1,
                       const float* __restrict__ s2, const float* __restrict__ s3,
                       const float* __restrict__ s4, const float* __restrict__ s5,
                       unsigned short* __restrict__ dst,
                       int* __restrict__ cur, int* __restrict__ ovfcnt, int N4,
                       const float* __restrict__ xin, unsigned short* __restrict__ x16,
                       int nTot){
  int i = blockIdx.x*blockDim.x + threadIdx.x;
  if (i < N4) cur[i] = 0;
  if (i == 0){ ovfcnt[0] = 0; }
  int base = i*8;
  if (base < nTot){
    const float4* xp = (const float4*)(xin + base);
    float4 a = xp[0], b = xp[1];
    us8 t;
    t[0]=f2h(a.x); t[1]=f2h(a.y); t[2]=f2h(a.z); t[3]=f2h(a.w);
    t[4]=f2h(b.x); t[5]=f2h(b.y); t[6]=f2h(b.z); t[7]=f2h(b.w);
    *(us8*)(x16 + base) = t;
  }
  if (i >= 65792) return;
  const float* s; int off;
  if      (i < 12288){ s = s0; off = i; }
  else if (i < 24576){ s = s1; off = i - 12288; }
  else if (i < 36864){ s = s2; off = i - 24576; }
  else if (i < 49152){ s = s3; off = i - 36864; }
  else if (i < 49408){ s = s4; off = i - 49152; }
  else               { s = s5; off = i - 49408; }
  dst[i] = f2bf(s[off]);
}

// 4 sub-buckets (sub = xcc>>1: XCD-pair local lines), 16 slots each; device-
// scope counter atomic (spans 2 XCDs; scope neutral per r11). Slot = int4
// {src, ea01 bf16x2, ea23 bf16x2, 0}; 2 edges/thread for MLP.
__global__ void k_bucket(const int* __restrict__ ei, const float* __restrict__ ea,
                         int* __restrict__ cur, int4* __restrict__ bkt,
                         int* __restrict__ ovfcnt, int* __restrict__ ovf,
                         int E, int N){
  unsigned xcc;
  asm volatile("s_getreg_b32 %0, hwreg(HW_REG_XCC_ID)" : "=s"(xcc));
  int sub = (int)((xcc >> 1) & 3u);  // XCD-pair id (0..3)
  int base = blockIdx.x*512;
#pragma unroll
  for (int half = 0; half < 2; ++half){
    int e = base + half*256 + threadIdx.x;
    if (e >= E) continue;
    int s = ei[e];
    int d = ei[E + e];
    size_t sb = (size_t)sub*N + d;
    int pos = atomicAdd(&cur[sb], 1);
    if (pos < SLOTS){
      float4 v = *(const float4*)(ea + (size_t)e*4);
      int4 p;
      p.x = s;
      p.y = (int)(((unsigned)f2bf(v.y) << 16) | (unsigned)f2bf(v.x));
      p.z = (int)(((unsigned)f2bf(v.w) << 16) | (unsigned)f2bf(v.z));
      p.w = 0;
      bkt[sb*SLOTS + pos] = p;
    } else {
      int o = atomicAdd(ovfcnt, 1);
      if (o < OVF_MAX) ovf[o] = e;
    }
  }
}

// 8-deep row-load batch for one node's mask; all lanes load element d of the
// extracted rows. Loads are independent -> up to 8 in flight per node.
#define GATHER8(MM, SRC, A)                                                \
  {                                                                        \
    unsigned long long m2 = (MM);                                          \
    if (m2){                                                               \
      int l0=(int)__builtin_ctzll(m2); m2 &= m2-1;                         \
      A[0] = h2f(x16[(size_t)__shfl((SRC), l0)*64 + d]);                   \
      if (m2){                                                             \
        int l1=(int)__builtin_ctzll(m2); m2 &= m2-1;                       \
        A[1] = h2f(x16[(size_t)__shfl((SRC), l1)*64 + d]);                 \
        if (m2){                                                           \
          int l2=(int)__builtin_ctzll(m2); m2 &= m2-1;                     \
          A[2] = h2f(x16[(size_t)__shfl((SRC), l2)*64 + d]);               \
          if (m2){                                                         \
            int l3=(int)__builtin_ctzll(m2); m2 &= m2-1;                   \
            A[3] = h2f(x16[(size_t)__shfl((SRC), l3)*64 + d]);             \
            if (m2){                                                       \
              int l4=(int)__builtin_ctzll(m2); m2 &= m2-1;                 \
              A[4] = h2f(x16[(size_t)__shfl((SRC), l4)*64 + d]);           \
              if (m2){                                                     \
                int l5=(int)__builtin_ctzll(m2); m2 &= m2-1;               \
                A[5] = h2f(x16[(size_t)__shfl((SRC), l5)*64 + d]);         \
                if (m2){                                                   \
                  int l6=(int)__builtin_ctzll(m2); m2 &= m2-1;             \
                  A[6] = h2f(x16[(size_t)__shfl((SRC), l6)*64 + d]);       \
                  if (m2){                                                 \
                    int l7=(int)__builtin_ctzll(m2); m2 &= m2-1;           \
                    A[7] = h2f(x16[(size_t)__shfl((SRC), l7)*64 + d]);     \
                  }                                                        \
                }                                                          \
              }                                                            \
            }                                                              \
          }                                                                \
        }                                                                  \
      }                                                                    \
    }                                                                      \
    (MM) = m2;                                                             \
  }

// gather 4 nodes per wave into LDS mt rows w*4..w*4+3 (pipelined: all 4
// nodes' loads interleaved, up to 32 row loads in flight), then apply this
// wave's overflow edges. Lane = dim d; lane owns slot (sub=d>>4, k=d&15).
__device__ __forceinline__ void gather4_ovf(
    const int* __restrict__ cur, const int4* __restrict__ bkt,
    const float* __restrict__ xin, const unsigned short* __restrict__ x16,
    const float* __restrict__ w_edge, const float* __restrict__ b_edge,
    const int* __restrict__ ei, const float* __restrict__ ea,
    const int* __restrict__ ovf, int cnt, int E,
    float (*mt)[68], int tile, int w, int lane, int N){
  int d = lane;
  int sub = d >> 4, k = d & 15;
  float4 wv = *(const float4*)(w_edge + d*4);
  float be = b_edge[d];
  int n0 = tile*16 + w*4;

  // ---- phase A: 4x cur + 4x self-row loads (8 independent, in flight)
  int nc[4]; int myc[4]; float selfv[4];
#pragma unroll
  for (int nl = 0; nl < 4; ++nl){
    int n = n0 + nl;
    nc[nl] = n < N ? n : N-1;
    myc[nl] = cur[(size_t)sub*N + nc[nl]];
    selfv[nl] = xin[(size_t)nc[nl]*64 + d];
  }
  // ---- phase B: valid + 4x bucket-slot loads (in flight) + ballot masks
  bool valid[4]; int4 ps[4];
#pragma unroll
  for (int nl = 0; nl < 4; ++nl){
    valid[nl] = k < min(myc[nl], SLOTS);
    int4 z; z.x = 0; z.y = 0; z.z = 0; z.w = 0;
    ps[nl] = valid[nl] ? bkt[((size_t)sub*N + nc[nl])*SLOTS + k] : z;
  }
  unsigned long long mm[4]; int src[4];
#pragma unroll
  for (int nl = 0; nl < 4; ++nl){
    mm[nl] = __ballot(valid[nl]);
    src[nl] = ps[nl].x;
  }
  // ---- phase C: interleaved row gather, up to 32 loads in flight per batch
  float acc[4];
#pragma unroll
  for (int nl = 0; nl < 4; ++nl) acc[nl] = 0.f;
  while (mm[0] | mm[1] | mm[2] | mm[3]){
    float a[4][8];
#pragma unroll
    for (int nl = 0; nl < 4; ++nl){
#pragma unroll
      for (int jj = 0; jj < 8; ++jj) a[nl][jj] = 0.f;
      GATHER8(mm[nl], src[nl], a[nl]);
    }
#pragma unroll
    for (int nl = 0; nl < 4; ++nl)
      acc[nl] += ((a[nl][0]+a[nl][1])+(a[nl][2]+a[nl][3]))
               + ((a[nl][4]+a[nl][5])+(a[nl][6]+a[nl][7]));
  }
  // ---- phase D: deg + ea butterflies (VALU, off the load critical path)
#pragma unroll
  for (int nl = 0; nl < 4; ++nl){
    int contrib = (k == 0) ? myc[nl] : 0;
#pragma unroll
    for (int off = 1; off < 64; off <<= 1) contrib += __shfl_xor(contrib, off);
    float ex = 0.f, ey = 0.f, ez = 0.f, ew = 0.f;
    if (valid[nl]){
      ex = bf2f((unsigned short)(ps[nl].y & 0xffff));
      ey = bf2f((unsigned short)(((unsigned)ps[nl].y) >> 16));
      ez = bf2f((unsigned short)(ps[nl].z & 0xffff));
      ew = bf2f((unsigned short)(((unsigned)ps[nl].z) >> 16));
    }
#pragma unroll
    for (int off = 1; off < 64; off <<= 1){
      ex += __shfl_xor(ex, off);
      ey += __shfl_xor(ey, off);
      ez += __shfl_xor(ez, off);
      ew += __shfl_xor(ew, off);
    }
    mt[w*4 + nl][d] = selfv[nl] + (float)(contrib + 1) * be + acc[nl]
                    + ex*wv.x + ey*wv.y + ez*wv.z + ew*wv.w;
  }
  // ---- overflow edges for rows owned by this wave (identical to old k_ovf)
  int lo = tile*16;
  for (int base = 0; base < cnt; base += 64){
    int idx = base + lane;
    int eid = (idx < cnt) ? ovf[idx] : -1;
    int dst = (eid >= 0) ? ei[(size_t)E + eid] : -1;
    int rel = dst - lo;
    bool hit = (eid >= 0) && (rel >= 0) && (rel < 16) && ((rel >> 2) == w);
    unsigned long long hm = __ballot(hit);
    while (hm){
      int l = (int)__builtin_ctzll(hm); hm &= hm - 1;
      int e2 = __shfl(eid, l);
      int r2 = __shfl(rel, l);
      int s2 = ei[e2];
      float4 v = *(const float4*)(ea + (size_t)e2*4);
      float addv = xin[(size_t)s2*64 + d] + v.x*wv.x + v.y*wv.y + v.z*wv.z + v.w*wv.w;
      mt[r2][d] += addv;
    }
  }
}

// GRU MFMA core: wave j owns output cols [16j,16j+16) = w-row-blocks {j,j+4,j+8}.
// A-frags from LDS mt ([16][68] pad: 2-way banks, 272B rows 16B-aligned).
__device__ __forceinline__ void gru3(
    const float (*mt)[68], const float* __restrict__ x,
    const unsigned short* __restrict__ wih, const unsigned short* __restrict__ whh,
    int tile, int j, int col, int quad, int N,
    floatx4* ai, floatx4* ah){
  int na = tile*16 + col; if (na > N-1) na = N-1;
  bf16x8 am[2], ax[2];
#pragma unroll
  for (int ks = 0; ks < 2; ++ks){
    int kb = ks*32 + quad*8;
    const float* mrow = &mt[col][kb];
    float4 lo = *(const float4*)mrow, hi = *(const float4*)(mrow + 4);
    us8 tm;
    tm[0]=f2bf(lo.x); tm[1]=f2bf(lo.y); tm[2]=f2bf(lo.z); tm[3]=f2bf(lo.w);
    tm[4]=f2bf(hi.x); tm[5]=f2bf(hi.y); tm[6]=f2bf(hi.z); tm[7]=f2bf(hi.w);
    am[ks] = __builtin_bit_cast(bf16x8, tm);
    const float4* xp = (const float4*)(x + (size_t)na*64 + kb);
    float4 xlo = xp[0], xhi = xp[1];
    us8 tx;
    tx[0]=f2bf(xlo.x); tx[1]=f2bf(xlo.y); tx[2]=f2bf(xlo.z); tx[3]=f2bf(xlo.w);
    tx[4]=f2bf(xhi.x); tx[5]=f2bf(xhi.y); tx[6]=f2bf(xhi.z); tx[7]=f2bf(xhi.w);
    ax[ks] = __builtin_bit_cast(bf16x8, tx);
  }
#pragma unroll
  for (int g = 0; g < 3; ++g){ ai[g] = (floatx4)0.f; ah[g] = (floatx4)0.f; }
#pragma unroll
  for (int g = 0; g < 3; ++g){
    int r = (g*4 + j)*16 + col;
#pragma unroll
    for (int ks = 0; ks < 2; ++ks){
      int kb = ks*32 + quad*8;
      bf16x8 bi = __builtin_bit_cast(bf16x8, *(const us8*)(wih + (size_t)r*64 + kb));
      ai[g] = __builtin_amdgcn_mfma_f32_16x16x32_bf16(am[ks], bi, ai[g], 0,0,0);
      bf16x8 bh = __builtin_bit_cast(bf16x8, *(const us8*)(whh + (size_t)r*64 + kb));
      ah[g] = __builtin_amdgcn_mfma_f32_16x16x32_bf16(ax[ks], bh, ah[g], 0,0,0);
    }
  }
}

// Layer 1: gather + ovf + GRU -> h (fp32) + h16 (fp16 mirror). Reads x only.
__global__ void __launch_bounds__(256) k_fused1(
    const int* __restrict__ cur, const int4* __restrict__ bkt,
    const float* __restrict__ x, const unsigned short* __restrict__ x16,
    const float* __restrict__ w_edge, const float* __restrict__ b_edge,
    const int* __restrict__ ei, const float* __restrict__ ea,
    const int* __restrict__ ovf, const int* __restrict__ ovfcnt, int E,
    const unsigned short* __restrict__ wih, const unsigned short* __restrict__ whh,
    const float* __restrict__ b_ih, const float* __restrict__ b_hh,
    float* __restrict__ hout, unsigned short* __restrict__ h16out,
    int tiles, int N){
  __shared__ __align__(16) float mt[16][68];
  int tile = blockIdx.x; if (tile >= tiles) return;
  int w = threadIdx.x >> 6, lane = threadIdx.x & 63;
  int cnt = *ovfcnt; if (cnt > OVF_MAX) cnt = OVF_MAX;
  gather4_ovf(cur, bkt, x, x16, w_edge, b_edge, ei, ea, ovf, cnt, E,
              mt, tile, w, lane, N);
  __syncthreads();   // mt complete across waves

  int col = lane & 15, quad = lane >> 4, j = w;
  floatx4 ai[3], ah[3];
  gru3(mt, x, wih, whh, tile, j, col, quad, N, ai, ah);

  int dd = j*16 + col;
  float bir = b_ih[dd],      bhr = b_hh[dd];
  float biz = b_ih[64+dd],   bhz = b_hh[64+dd];
  float bin = b_ih[128+dd],  bhn = b_hh[128+dd];
#pragma unroll
  for (int rg = 0; rg < 4; ++rg){
    int node = tile*16 + quad*4 + rg;
    if (node >= N) continue;
    float rr = sigm(ai[0][rg] + bir + ah[0][rg] + bhr);
    float zz = sigm(ai[1][rg] + biz + ah[1][rg] + bhz);
    float nn = tanhf(ai[2][rg] + bin + rr*(ah[2][rg] + bhn));
    float xv = x[(size_t)node*64 + dd];
    float hv = fmaxf((1.f - zz)*nn + zz*xv, 0.f);
    hout[(size_t)node*64 + dd] = hv;
    h16out[(size_t)node*64 + dd] = f2h(hv);
  }
}

// Layer 2 + MoE: gather + ovf + GRU -> bf16 h-frags in swizzled LDS -> MoE -> v.
// Reads h/h16 only (no in-place hazard); writes v only.
__global__ void __launch_bounds__(256) k_fused2(
    const int* __restrict__ cur, const int4* __restrict__ bkt,
    const float* __restrict__ h, const unsigned short* __restrict__ h16,
    const float* __restrict__ w_edge, const float* __restrict__ b_edge,
    const int* __restrict__ ei, const float* __restrict__ ea,
    const int* __restrict__ ovf, const int* __restrict__ ovfcnt, int E,
    const unsigned short* __restrict__ wih, const unsigned short* __restrict__ whh,
    const float* __restrict__ b_ih, const float* __restrict__ b_hh,
    const unsigned short* __restrict__ gate_w, const float* __restrict__ gate_b,
    const unsigned short* __restrict__ exp_w,  const float* __restrict__ exp_b,
    float* __restrict__ v_out, int tiles, int N){
  __shared__ __align__(16) float mt[16][68];
  __shared__ __align__(16) unsigned short ht16s[1024];  // bf16, XOR-swizzled
  __shared__ float gsm[16][4];
  __shared__ float vsm[4][16][65];
  int tile = blockIdx.x; if (tile >= tiles) return;
  int w = threadIdx.x >> 6, lane = threadIdx.x & 63;
  int cnt = *ovfcnt; if (cnt > OVF_MAX) cnt = OVF_MAX;
  gather4_ovf(cur, bkt, h, h16, w_edge, b_edge, ei, ea, ovf, cnt, E,
              mt, tile, w, lane, N);
  __syncthreads();   // mt complete

  int col = lane & 15, quad = lane >> 4, j = w;
  floatx4 ai[3], ah[3];
  gru3(mt, h, wih, whh, tile, j, col, quad, N, ai, ah);

  int dd = j*16 + col;
  {
    float bir = b_ih[dd],      bhr = b_hh[dd];
    float biz = b_ih[64+dd],   bhz = b_hh[64+dd];
    float bin = b_ih[128+dd],  bhn = b_hh[128+dd];
#pragma unroll
    for (int rg = 0; rg < 4; ++rg){
      int nloc = quad*4 + rg;
      int node = tile*16 + nloc;
      int na2 = node < N ? node : N-1;
      float rr = sigm(ai[0][rg] + bir + ah[0][rg] + bhr);
      float zz = sigm(ai[1][rg] + biz + ah[1][rg] + bhz);
      float nn = tanhf(ai[2][rg] + bin + rr*(ah[2][rg] + bhn));
      float xv = h[(size_t)na2*64 + dd];
      float hv = fmaxf((1.f - zz)*nn + zz*xv, 0.f);
      // swizzled bf16 store for the MoE A-fragment ((node&7)<<4 XOR: 2-way max)
      int addr = (nloc*128 + dd*2) ^ ((nloc & 7) << 4);
      *(unsigned short*)((char*)ht16s + addr) = f2bf(hv);
    }
  }
  __syncthreads();   // h-tile ready

  // ---- MoE phase: wave j = expert j; wave 0 also does the gate ----
  bf16x8 a2[2];
#pragma unroll
  for (int ks = 0; ks < 2; ++ks){
    int badd = (col*128 + ks*64 + quad*16) ^ ((col & 7) << 4);
    a2[ks] = __builtin_bit_cast(bf16x8, *(const us8*)((const char*)ht16s + badd));
  }
  if (j == 0){
    floatx4 accg = (floatx4)0.f;
#pragma unroll
    for (int ks = 0; ks < 2; ++ks){
      int kb = ks*32 + quad*8;
      us8 braw = {0,0,0,0,0,0,0,0};
      if (col < 4) braw = *(const us8*)(gate_w + col*64 + kb);
      accg = __builtin_amdgcn_mfma_f32_16x16x32_bf16(a2[ks], __builtin_bit_cast(bf16x8, braw), accg, 0,0,0);
    }
    if (col < 4){
      float gb = gate_b[col];
#pragma unroll
      for (int rg = 0; rg < 4; ++rg) gsm[quad*4+rg][col] = accg[rg] + gb;
    }
  }
  floatx4 acc2[4];
#pragma unroll
  for (int nt = 0; nt < 4; ++nt) acc2[nt] = (floatx4)0.f;
#pragma unroll
  for (int nt = 0; nt < 4; ++nt)
#pragma unroll
    for (int ks = 0; ks < 2; ++ks){
      int kb = ks*32 + quad*8;
      bf16x8 b = __builtin_bit_cast(bf16x8,
          *(const us8*)(exp_w + ((size_t)j*64 + nt*16 + col)*64 + kb));
      acc2[nt] = __builtin_amdgcn_mfma_f32_16x16x32_bf16(a2[ks], b, acc2[nt], 0,0,0);
    }
  __syncthreads();   // gsm ready

#pragma unroll
  for (int rg = 0; rg < 4; ++rg){
    int nrow = quad*4 + rg;
    float g0=gsm[nrow][0], g1=gsm[nrow][1], g2=gsm[nrow][2], g3=gsm[nrow][3];
    float mx = fmaxf(fmaxf(g0,g1), fmaxf(g2,g3));
    float e0=__expf(g0-mx), e1=__expf(g1-mx), e2=__expf(g2-mx), e3=__expf(g3-mx);
    float we = ((j==0)?e0:(j==1)?e1:(j==2)?e2:e3) / (e0+e1+e2+e3);
#pragma unroll
    for (int nt = 0; nt < 4; ++nt){
      int o = nt*16 + col;
      vsm[j][nrow][o] = we * fmaxf(acc2[nt][rg] + exp_b[j*64 + o], 0.f);
    }
  }
  __syncthreads();   // vsm ready

  for (int idx = threadIdx.x; idx < 1024; idx += 256){
    int nrow = idx >> 6, o = idx & 63;
    int node = tile*16 + nrow;
    if (node < N)
      v_out[(size_t)node*64 + o] = vsm[0][nrow][o] + vsm[1][nrow][o]
                                 + vsm[2][nrow][o] + vsm[3][nrow][o];
  }
}

__device__ __forceinline__ int lower_bound_i(const int* __restrict__ a, int n, int key){
  int lo = 0, hi = n;
  while (lo < hi){ int mid = (lo + hi) >> 1; if (a[mid] < key) lo = mid + 1; else hi = mid; }
  return lo;
}

// stage 1: B*PS blocks; block (g,s) reduces 1/PS of graph g's nodes.
__global__ void __launch_bounds__(256) k_pool(
    const float* __restrict__ v, const int* __restrict__ batch, int N,
    float* __restrict__ partial){
  __shared__ float red[4][64];
  int g = blockIdx.x / PS, s = blockIdx.x % PS;
  int t = threadIdx.x, d = t & 63, r = t >> 6;
  int start = lower_bound_i(batch, N, g);
  int end   = lower_bound_i(batch, N, g + 1);
  int len = end - start;
  int per = (len + PS - 1) / PS;
  int s0 = start + s*per;
  int s1 = s0 + per; if (s1 > end) s1 = end;
  float acc = 0.f;
  for (int i = s0 + r; i < s1; i += 4)
    acc += v[(size_t)i*64 + d];
  red[r][d] = acc;
  __syncthreads();
  if (r == 0)
    partial[(size_t)blockIdx.x*64 + d] = red[0][d] + red[1][d] + red[2][d] + red[3][d];
}

// stage 2: B blocks; sum PS partials, mean, write emb twice + logits head.
__global__ void __launch_bounds__(64) k_head(
    const float* __restrict__ partial, const int* __restrict__ batch, int N, int B,
    const float* __restrict__ ldxb,
    const float* __restrict__ proj_w, const float* __restrict__ proj_b,
    const float* __restrict__ fc_w, const float* __restrict__ fc_b,
    float* __restrict__ out){
  __shared__ float ges[64];
  int b = blockIdx.x, d = threadIdx.x;
  int start = lower_bound_i(batch, N, b);
  int end   = lower_bound_i(batch, N, b + 1);
  float sum = 0.f;
#pragma unroll
  for (int s = 0; s < PS; ++s)
    sum += partial[((size_t)b*PS + s)*64 + d];
  float ge = sum / fmaxf((float)(end - start), 1.f);
  ges[d] = ge;
  out[(size_t)b*64 + d]                = ge;
  out[(size_t)B*64 + (size_t)b*64 + d] = ge;
  __syncthreads();
  if (d < 10){
    float acc = fc_b[d];
    float fl = ldxb[b];
    const float* fr = fc_w + d*164;
    for (int p = 0; p < 100; ++p) acc += (fl*proj_w[p] + proj_b[p]) * fr[p];
    for (int dd = 0; dd < 64; ++dd) acc += ges[dd]*fr[100 + dd];
    out[(size_t)B*128 + (size_t)b*10 + d] = acc;
  }
}

extern "C" void kernel_launch(void* const* d_in, const int* in_sizes, int n_in,
                              void* d_out, int out_size, void* d_ws, size_t ws_size,
                              hipStream_t stream){
  const float* x      = (const float*)d_in[0];
  const int*   ei     = (const int*)d_in[1];
  const float* ea     = (const float*)d_in[2];
  const int*   batch  = (const int*)d_in[3];
  const float* ldxb   = (const float*)d_in[4];
  const float* w_edge1= (const float*)d_in[5];
  const float* b_edge1= (const float*)d_in[6];
  const float* w_ih1  = (const float*)d_in[7];
  const float* w_hh1  = (const float*)d_in[8];
  const float* b_ih1  = (const float*)d_in[9];
  const float* b_hh1  = (const float*)d_in[10];
  const float* w_edge2= (const float*)d_in[11];
  const float* b_edge2= (const float*)d_in[12];
  const float* w_ih2  = (const float*)d_in[13];
  const float* w_hh2  = (const float*)d_in[14];
  const float* b_ih2  = (const float*)d_in[15];
  const float* b_hh2  = (const float*)d_in[16];
  const float* gate_w = (const float*)d_in[17];
  const float* gate_b = (const float*)d_in[18];
  const float* exp_w  = (const float*)d_in[19];
  const float* exp_b  = (const float*)d_in[20];
  const float* proj_w = (const float*)d_in[21];
  const float* proj_b = (const float*)d_in[22];
  const float* fc_w   = (const float*)d_in[23];
  const float* fc_b   = (const float*)d_in[24];
  float* out = (float*)d_out;

  int N = in_sizes[0] / 64;
  int E = in_sizes[1] / 2;
  int B = in_sizes[4];
  int tiles = (N + 15) / 16;
  int nTot = N * 64;

  // workspace layout (all segment sizes multiples of 16B)
  float*   v       = (float*)d_ws;                      // N*64 f32 (MoE output)
  float*   h       = v + (size_t)nTot;                  // N*64 f32
  int4*    bkt     = (int4*)(h + (size_t)nTot);         // N*64 int4 (4 subs x 16 slots)
  int*     cur     = (int*)(bkt + (size_t)nTot);        // 8*N alloc; 4*N used [sub*N+n]
  int*     ovfcnt  = cur + (size_t)N*8;                 // 4 i32 (padded)
  int*     ovf     = ovfcnt + 4;                        // OVF_MAX i32
  unsigned short* wbf = (unsigned short*)(ovf + OVF_MAX); // 65792 bf16
  float*   partial = (float*)(wbf + 65792);             // B*PS*64 f32
  unsigned short* x16 = (unsigned short*)(partial + (size_t)B*PS*64); // N*64 fp16
  unsigned short* h16 = x16 + (size_t)nTot;             // N*64 fp16
  unsigned short* wih1bf = wbf;
  unsigned short* whh1bf = wbf + 12288;
  unsigned short* wih2bf = wbf + 24576;
  unsigned short* whh2bf = wbf + 36864;
  unsigned short* gatebf = wbf + 49152;
  unsigned short* expbf  = wbf + 49408;

  dim3 blk(256);
  int edgeBlocks = (E + 511)/512;       // 2 edges per thread
  int N4 = N*4;
  int initThreads = N4 > 65792 ? N4 : 65792;
  if (nTot/8 > initThreads) initThreads = nTot/8;
  int initBlocks = (initThreads + 255)/256;

  k_init<<<initBlocks, blk, 0, stream>>>(w_ih1, w_hh1, w_ih2, w_hh2, gate_w, exp_w,
                                         wbf, cur, ovfcnt, N4, x, x16, nTot);
  k_bucket<<<edgeBlocks, blk, 0, stream>>>(ei, ea, cur, bkt, ovfcnt, ovf, E, N);
  // ---- layer 1: gather + ovf + GRU fused ----
  k_fused1<<<tiles, blk, 0, stream>>>(cur, bkt, x, x16, w_edge1, b_edge1,
                                      ei, ea, ovf, ovfcnt, E,
                                      wih1bf, whh1bf, b_ih1, b_hh1,
                                      h, h16, tiles, N);
  // ---- layer 2 + MoE fused ----
  k_fused2<<<tiles, blk, 0, stream>>>(cur, bkt, h, h16, w_edge2, b_edge2,
                                      ei, ea, ovf, ovfcnt, E,
                                      wih2bf, whh2bf, b_ih2, b_hh2,
                                      gatebf, gate_b, expbf, exp_b,
                                      v, tiles, N);
  // ---- two-stage segmented-mean pool + heads ----
  k_pool<<<B*PS, blk, 0, stream>>>(v, batch, N, partial);
  k_head<<<B, 64, 0, stream>>>(partial, batch, N, B, ldxb, proj_w, proj_b, fc_w, fc_b, out);
}